// Round 3
// baseline (167.882 us; speedup 1.0000x reference)
//
#include <hip/hip_runtime.h>
#include <hip/hip_bf16.h>
#include <math.h>

// y[b,l,d] = x[b,l,d] * softplus((x@W1+b1)[b,l,d]) * sum_n((x@W2+b2)*(x@W3+b3))[b,l,n]

namespace {

constexpr int Dd   = 1024;
constexpr int ROWS = 8192;

typedef __bf16 bf16x8 __attribute__((ext_vector_type(8)));
typedef float  floatx4 __attribute__((ext_vector_type(4)));

__device__ __forceinline__ float softplus_fast(float v) {
    float l = __logf(1.0f + __expf(v));
    return v > 15.0f ? v : l;
}
__device__ __forceinline__ float bf_lo(unsigned short u) {
    union { unsigned q; float f; } c; c.q = ((unsigned)u) << 16; return c.f;
}

// ---------------------------------------------------------------------------
// prep: blocks 0..511  — 16 rows each: x fp32 -> bf16 Xb (loads land directly
//       in MFMA A-frag layout: row=lane&15, k=quad*8) and s[row] via MFMA
//       against W2/W3 frags loaded straight from L2. 4 waves K-split 256.
//       blocks 512..767 — W1 [k][n] fp32 -> W1t [n][k] bf16 (64x64 tiles).
// No big LDS, no K-loop barriers.
// ---------------------------------------------------------------------------
__global__ __launch_bounds__(256, 2) void prep_kernel(
    const float* __restrict__ X, const float* __restrict__ W1,
    const float* __restrict__ W2, const float* __restrict__ b2,
    const float* __restrict__ W3, const float* __restrict__ b3,
    __bf16* __restrict__ Xb, __bf16* __restrict__ W1t, float* __restrict__ Sv)
{
    const int t = threadIdx.x;

    if (blockIdx.x >= 512) {
        // ---- W1 transpose tile path ----
        __shared__ __bf16 tile[64][66];
        const int bidx = blockIdx.x - 512;
        const int bi = bidx >> 4, bj = bidx & 15;   // k tile, n tile
        const int c = t & 63, r4 = t >> 6;
        #pragma unroll
        for (int i = 0; i < 16; ++i) {
            const int r = i * 4 + r4;
            tile[r][c] = (__bf16)W1[(size_t)(bi * 64 + r) * Dd + bj * 64 + c];
        }
        __syncthreads();
        #pragma unroll
        for (int i = 0; i < 16; ++i) {
            const int r = i * 4 + r4;
            W1t[(size_t)(bj * 64 + r) * Dd + bi * 64 + c] = tile[c][r];
        }
        return;
    }

    // ---- x path ----
    __shared__ float red[4][2][16][16];   // [wave][B/C][row][n]
    __shared__ float pbuf[16][16];        // [row][n]
    const int w = t >> 6, lane = t & 63;
    const int l15 = lane & 15, quad = lane >> 4;
    const int row0 = blockIdx.x * 16;
    const int kw = w * 256;
    const size_t xoff = (size_t)(row0 + l15) * Dd;

    floatx4 acc0 = {0.f, 0.f, 0.f, 0.f}, acc1 = {0.f, 0.f, 0.f, 0.f};
    #pragma unroll
    for (int ks = 0; ks < 8; ++ks) {
        const int k0 = kw + ks * 32 + quad * 8;
        const float4 xa = *(const float4*)&X[xoff + k0];
        const float4 xb = *(const float4*)&X[xoff + k0 + 4];
        bf16x8 af;
        af[0] = (__bf16)xa.x; af[1] = (__bf16)xa.y;
        af[2] = (__bf16)xa.z; af[3] = (__bf16)xa.w;
        af[4] = (__bf16)xb.x; af[5] = (__bf16)xb.y;
        af[6] = (__bf16)xb.z; af[7] = (__bf16)xb.w;
        *(bf16x8*)&Xb[xoff + k0] = af;   // 16B coalesced store
        bf16x8 w2f, w3f;
        #pragma unroll
        for (int j = 0; j < 8; ++j) {
            w2f[j] = (__bf16)W2[(size_t)(k0 + j) * 16 + l15];
            w3f[j] = (__bf16)W3[(size_t)(k0 + j) * 16 + l15];
        }
        acc0 = __builtin_amdgcn_mfma_f32_16x16x32_bf16(af, w2f, acc0, 0, 0, 0);
        acc1 = __builtin_amdgcn_mfma_f32_16x16x32_bf16(af, w3f, acc1, 0, 0, 0);
    }
    // C/D layout: col(n) = l15, row = quad*4 + r
    #pragma unroll
    for (int r = 0; r < 4; ++r) {
        red[w][0][quad * 4 + r][l15] = acc0[r];
        red[w][1][quad * 4 + r][l15] = acc1[r];
    }
    __syncthreads();
    {
        const int r = t & 15, n = t >> 4;
        if (n < 16) {
            float B = b2[n], C = b3[n];
            #pragma unroll
            for (int ww = 0; ww < 4; ++ww) {
                B += red[ww][0][r][n];
                C += red[ww][1][r][n];
            }
            pbuf[r][n] = B * C;
        }
    }
    __syncthreads();
    if (t < 16) {
        float s = 0.f;
        #pragma unroll
        for (int n = 0; n < 16; ++n) s += pbuf[t][n];
        Sv[row0 + t] = s;
    }
}

// ---------------------------------------------------------------------------
// gemm: barrier-free, LDS-free. Each wave owns a 64x64 tile; A/B fragments
// loaded directly global->VGPR (full-64B-line coalesced), double-buffered in
// registers so the compiler pipelines with fine-grained vmcnt. Per-XCD
// swizzle: rb tied to blockIdx&7 so A-slice (2MB) + W1t (2MB) fit that
// XCD's 4MB L2. Fused epilogue y = xb * softplus(g+b1) * s[row].
// ---------------------------------------------------------------------------
__global__ __launch_bounds__(256, 2) void gemm_kernel(
    const __bf16* __restrict__ Xb, const __bf16* __restrict__ W1t,
    const float* __restrict__ Sv, const float* __restrict__ b1,
    float* __restrict__ Y)
{
    const int t = threadIdx.x, lane = t & 63;
    const int w = t >> 6, wm = w & 1, wn = w >> 1;
    const int l15 = lane & 15, quad = lane >> 4;
    const int b  = blockIdx.x;
    const int rb = (b & 7) * 8 + ((b >> 3) & 7);   // XCD-major row blocking
    const int cb = b >> 6;
    const int row0 = rb * 128, col0 = cb * 128;

    const __bf16* Ap[4]; const __bf16* Bp[4];
    #pragma unroll
    for (int mt = 0; mt < 4; ++mt)
        Ap[mt] = Xb + (size_t)(row0 + wm * 64 + mt * 16 + l15) * Dd + quad * 8;
    #pragma unroll
    for (int nt = 0; nt < 4; ++nt)
        Bp[nt] = W1t + (size_t)(col0 + wn * 64 + nt * 16 + l15) * Dd + quad * 8;

    floatx4 acc[4][4] = {};
    bf16x8 a0[4], b0[4], a1[4], b1f[4];

#define LOADF(AA, BB, K)                                                     \
    {                                                                        \
        _Pragma("unroll") for (int mt = 0; mt < 4; ++mt)                     \
            AA[mt] = *(const bf16x8*)(Ap[mt] + (K));                         \
        _Pragma("unroll") for (int nt = 0; nt < 4; ++nt)                     \
            BB[nt] = *(const bf16x8*)(Bp[nt] + (K));                         \
    }
#define MFMAF(AA, BB)                                                        \
    {                                                                        \
        _Pragma("unroll") for (int mt = 0; mt < 4; ++mt)                     \
            _Pragma("unroll") for (int nt = 0; nt < 4; ++nt)                 \
                acc[mt][nt] = __builtin_amdgcn_mfma_f32_16x16x32_bf16(       \
                    AA[mt], BB[nt], acc[mt][nt], 0, 0, 0);                   \
    }

    LOADF(a0, b0, 0);
    for (int k0 = 0; k0 < Dd - 64; k0 += 64) {
        LOADF(a1, b1f, k0 + 32);
        MFMAF(a0, b0);
        LOADF(a0, b0, k0 + 64);
        MFMAF(a1, b1f);
    }
    LOADF(a1, b1f, Dd - 32);
    MFMAF(a0, b0);
    MFMAF(a1, b1f);
#undef LOADF
#undef MFMAF

    // epilogue: C/D layout col = l15, row = quad*4 + rr
    float bias[4];
    #pragma unroll
    for (int nt = 0; nt < 4; ++nt) bias[nt] = b1[col0 + wn * 64 + nt * 16 + l15];

    #pragma unroll
    for (int mt = 0; mt < 4; ++mt) {
        #pragma unroll
        for (int rr = 0; rr < 4; ++rr) {
            const int row = row0 + wm * 64 + mt * 16 + quad * 4 + rr;
            const float sv = Sv[row];
            const unsigned short* xrow =
                (const unsigned short*)(Xb + (size_t)row * Dd + col0);
            float* yrow = Y + (size_t)row * Dd + col0;
            #pragma unroll
            for (int nt = 0; nt < 4; ++nt) {
                const int cl = wn * 64 + nt * 16 + l15;
                const float v  = acc[mt][nt][rr] + bias[nt];
                const float sp = softplus_fast(v);
                yrow[cl] = bf_lo(xrow[cl]) * sp * sv;
            }
        }
    }
}

} // namespace

extern "C" void kernel_launch(void* const* d_in, const int* in_sizes, int n_in,
                              void* d_out, int out_size, void* d_ws, size_t ws_size,
                              hipStream_t stream)
{
    const float* X  = (const float*)d_in[0];
    const float* W1 = (const float*)d_in[1];
    const float* b1 = (const float*)d_in[2];
    const float* W2 = (const float*)d_in[3];
    const float* b2 = (const float*)d_in[4];
    const float* W3 = (const float*)d_in[5];
    const float* b3 = (const float*)d_in[6];
    // d_in[7] = A is dead code in the reference.
    float* Y = (float*)d_out;

    // workspace: Xb (16 MB bf16) | W1t (2 MB bf16) | Sv (32 KB fp32)
    __bf16* Xb  = (__bf16*)d_ws;
    __bf16* W1t = (__bf16*)((char*)d_ws + (size_t)ROWS * Dd * 2);
    float*  Sv  = (float*)((char*)d_ws + (size_t)ROWS * Dd * 2 + (size_t)Dd * Dd * 2);

    hipLaunchKernelGGL(prep_kernel, dim3(768), dim3(256), 0, stream,
                       X, W1, W2, b2, W3, b3, Xb, W1t, Sv);
    hipLaunchKernelGGL(gemm_kernel, dim3((ROWS / 128) * (Dd / 128)), dim3(256), 0, stream,
                       Xb, W1t, Sv, b1, Y);
}

// Round 4
// 147.582 us; speedup vs baseline: 1.1375x; 1.1375x over previous
//
#include <hip/hip_runtime.h>
#include <hip/hip_bf16.h>
#include <math.h>

// y[b,l,d] = x[b,l,d] * softplus((x@W1+b1)[b,l,d]) * sum_n((x@W2+b2)*(x@W3+b3))[b,l,n]

#define GLB(p) ((const __attribute__((address_space(1))) void*)(p))
#define LDSP(p) ((__attribute__((address_space(3))) void*)(p))

namespace {

constexpr int Dd   = 1024;
constexpr int ROWS = 8192;

typedef __bf16 bf16x8 __attribute__((ext_vector_type(8)));
typedef float  floatx4 __attribute__((ext_vector_type(4)));

__device__ __forceinline__ float softplus_fast(float v) {
    float l = __logf(1.0f + __expf(v));
    return v > 15.0f ? v : l;
}
__device__ __forceinline__ float bf_lo(unsigned short u) {
    union { unsigned q; float f; } c; c.q = ((unsigned)u) << 16; return c.f;
}

// ---------------------------------------------------------------------------
// kernel0: 1 block — W2,W3 [k][16] fp32 -> W2t,W3t [16][k] bf16 (32 KB each).
// Must run before prep_kernel (stream-ordered).
// ---------------------------------------------------------------------------
__global__ __launch_bounds__(256) void w23_kernel(
    const float* __restrict__ W2, const float* __restrict__ W3,
    __bf16* __restrict__ W2t, __bf16* __restrict__ W3t)
{
    const int t  = threadIdx.x;
    const int n  = t >> 4;            // 0..15
    const int kc = (t & 15) * 64;     // 64-k chunk
    #pragma unroll
    for (int i8 = 0; i8 < 8; ++i8) {
        bf16x8 a, b;
        #pragma unroll
        for (int j = 0; j < 8; ++j) {
            const int k = kc + i8 * 8 + j;
            a[j] = (__bf16)W2[(size_t)k * 16 + n];
            b[j] = (__bf16)W3[(size_t)k * 16 + n];
        }
        *(bf16x8*)&W2t[(size_t)n * Dd + kc + i8 * 8] = a;
        *(bf16x8*)&W3t[(size_t)n * Dd + kc + i8 * 8] = b;
    }
}

// ---------------------------------------------------------------------------
// prep: blocks 0..511 — 16 rows each: x fp32 -> bf16 Xb (loads land directly
//       in MFMA A-frag layout) and s[row] via MFMA against W2t/W3t b128 frags
//       (L1/L2-hot). 4 waves K-split 256 each.
//       blocks 512..767 — W1 [k][n] fp32 -> W1t [n][k] bf16 (64x64 tiles).
// ---------------------------------------------------------------------------
__global__ __launch_bounds__(256, 4) void prep_kernel(
    const float* __restrict__ X, const float* __restrict__ W1,
    const __bf16* __restrict__ W2t, const float* __restrict__ b2,
    const __bf16* __restrict__ W3t, const float* __restrict__ b3,
    __bf16* __restrict__ Xb, __bf16* __restrict__ W1t, float* __restrict__ Sv)
{
    const int t = threadIdx.x;

    if (blockIdx.x >= 512) {
        // ---- W1 transpose tile path ----
        __shared__ __bf16 tile[64][66];
        const int bidx = blockIdx.x - 512;
        const int bi = bidx >> 4, bj = bidx & 15;   // k tile, n tile
        const int c = t & 63, r4 = t >> 6;
        #pragma unroll
        for (int i = 0; i < 16; ++i) {
            const int r = i * 4 + r4;
            tile[r][c] = (__bf16)W1[(size_t)(bi * 64 + r) * Dd + bj * 64 + c];
        }
        __syncthreads();
        #pragma unroll
        for (int i = 0; i < 16; ++i) {
            const int r = i * 4 + r4;
            W1t[(size_t)(bj * 64 + r) * Dd + bi * 64 + c] = tile[c][r];
        }
        return;
    }

    // ---- x path ----
    __shared__ float red[4][2][16][16];   // [wave][B/C][row][n]
    __shared__ float pbuf[16][16];        // [row][n]
    const int w = t >> 6, lane = t & 63;
    const int l15 = lane & 15, quad = lane >> 4;
    const int row0 = blockIdx.x * 16;
    const int kw = w * 256;
    const size_t xoff = (size_t)(row0 + l15) * Dd;
    const size_t woff = (size_t)l15 * Dd;

    floatx4 acc0 = {0.f, 0.f, 0.f, 0.f}, acc1 = {0.f, 0.f, 0.f, 0.f};
    #pragma unroll
    for (int ks = 0; ks < 8; ++ks) {
        const int k0 = kw + ks * 32 + quad * 8;
        const float4 xa = *(const float4*)&X[xoff + k0];
        const float4 xb = *(const float4*)&X[xoff + k0 + 4];
        bf16x8 af;
        af[0] = (__bf16)xa.x; af[1] = (__bf16)xa.y;
        af[2] = (__bf16)xa.z; af[3] = (__bf16)xa.w;
        af[4] = (__bf16)xb.x; af[5] = (__bf16)xb.y;
        af[6] = (__bf16)xb.z; af[7] = (__bf16)xb.w;
        *(bf16x8*)&Xb[xoff + k0] = af;   // 16B store, A-frag layout
        const bf16x8 w2f = *(const bf16x8*)&W2t[woff + k0];
        const bf16x8 w3f = *(const bf16x8*)&W3t[woff + k0];
        acc0 = __builtin_amdgcn_mfma_f32_16x16x32_bf16(af, w2f, acc0, 0, 0, 0);
        acc1 = __builtin_amdgcn_mfma_f32_16x16x32_bf16(af, w3f, acc1, 0, 0, 0);
    }
    // C/D layout: col(n) = l15, row = quad*4 + r
    #pragma unroll
    for (int r = 0; r < 4; ++r) {
        red[w][0][quad * 4 + r][l15] = acc0[r];
        red[w][1][quad * 4 + r][l15] = acc1[r];
    }
    __syncthreads();
    {
        const int r = t & 15, n = t >> 4;
        if (n < 16) {
            float B = b2[n], C = b3[n];
            #pragma unroll
            for (int ww = 0; ww < 4; ++ww) {
                B += red[ww][0][r][n];
                C += red[ww][1][r][n];
            }
            pbuf[r][n] = B * C;
        }
    }
    __syncthreads();
    if (t < 16) {
        float s = 0.f;
        #pragma unroll
        for (int n = 0; n < 16; ++n) s += pbuf[t][n];
        Sv[row0 + t] = s;
    }
}

// ---------------------------------------------------------------------------
// gemm: 128x128 tile, BK=64 (16 K-steps — half the barrier drains of BK=32),
// global_load_lds 16B staging with XOR-slot swizzle (conflict-free frag
// reads), fused epilogue y = xb * softplus(g+b1) * s[row].
// LDS: A [0,16KB) rows 0..127 x 64k; B [16KB,32KB).
// ---------------------------------------------------------------------------
__global__ __launch_bounds__(256, 2) void gemm_kernel(
    const __bf16* __restrict__ Xb, const __bf16* __restrict__ W1t,
    const float* __restrict__ Sv, const float* __restrict__ b1,
    float* __restrict__ Y)
{
    __shared__ __attribute__((aligned(16))) __bf16 lds[16384];
    const int t = threadIdx.x, lane = t & 63;
    const int w = t >> 6, wm = w & 1, wn = w >> 1;
    const int l15 = lane & 15, quad = lane >> 4;
    const int cb = blockIdx.x & 7, rb = blockIdx.x >> 3;  // cb ~ XCD id
    const int row0 = rb * 128, col0 = cb * 128;

    floatx4 acc[4][4] = {};

    // staging: slot u (0..1023 per operand): p = u>>3 (row), s = u&7,
    // k-chunk c4 = s ^ (p&7). Thread t handles u = r*256 + t, r=0..3.
    const __bf16* gA[4]; const __bf16* gB[4];
    int dA[4], dB[4];
    #pragma unroll
    for (int r = 0; r < 4; ++r) {
        const int u = r * 256 + t;
        const int p = u >> 3, s = u & 7, c4 = s ^ (p & 7);
        gA[r] = Xb  + (size_t)(row0 + p) * Dd + c4 * 8;
        gB[r] = W1t + (size_t)(col0 + p) * Dd + c4 * 8;
        dA[r] = u * 8;
        dB[r] = 8192 + u * 8;
    }

    // frag-read slot math: row rl, chunk c (= ksub*4 + quad), slot = c^(rl&7)
    const int arl[4] = { wm * 64 + 0 * 16 + l15, wm * 64 + 1 * 16 + l15,
                         wm * 64 + 2 * 16 + l15, wm * 64 + 3 * 16 + l15 };
    const int brl[4] = { wn * 64 + 0 * 16 + l15, wn * 64 + 1 * 16 + l15,
                         wn * 64 + 2 * 16 + l15, wn * 64 + 3 * 16 + l15 };

    for (int k0 = 0; k0 < Dd; k0 += 64) {
        #pragma unroll
        for (int r = 0; r < 4; ++r) {
            __builtin_amdgcn_global_load_lds(GLB(gA[r] + k0), LDSP(&lds[dA[r]]), 16, 0, 0);
            __builtin_amdgcn_global_load_lds(GLB(gB[r] + k0), LDSP(&lds[dB[r]]), 16, 0, 0);
        }
        __syncthreads();

        #pragma unroll
        for (int ksub = 0; ksub < 2; ++ksub) {
            bf16x8 af[4], bfr[4];
            #pragma unroll
            for (int mt = 0; mt < 4; ++mt) {
                const int rl = arl[mt];
                const int sA = (ksub * 4 + quad) ^ (rl & 7);
                af[mt] = *(const bf16x8*)&lds[rl * 64 + sA * 8];
            }
            #pragma unroll
            for (int nt = 0; nt < 4; ++nt) {
                const int nl = brl[nt];
                const int sB = (ksub * 4 + quad) ^ (nl & 7);
                bfr[nt] = *(const bf16x8*)&lds[8192 + nl * 64 + sB * 8];
            }
            #pragma unroll
            for (int mt = 0; mt < 4; ++mt)
                #pragma unroll
                for (int nt = 0; nt < 4; ++nt)
                    acc[mt][nt] = __builtin_amdgcn_mfma_f32_16x16x32_bf16(
                        af[mt], bfr[nt], acc[mt][nt], 0, 0, 0);
        }
        __syncthreads();
    }

    // epilogue: C/D layout col = l15, row = quad*4 + rr
    float bias[4];
    #pragma unroll
    for (int nt = 0; nt < 4; ++nt) bias[nt] = b1[col0 + wn * 64 + nt * 16 + l15];

    #pragma unroll
    for (int mt = 0; mt < 4; ++mt) {
        #pragma unroll
        for (int rr = 0; rr < 4; ++rr) {
            const int row = row0 + wm * 64 + mt * 16 + quad * 4 + rr;
            const float sv = Sv[row];
            const unsigned short* xrow =
                (const unsigned short*)(Xb + (size_t)row * Dd + col0);
            float* yrow = Y + (size_t)row * Dd + col0;
            #pragma unroll
            for (int nt = 0; nt < 4; ++nt) {
                const int cl = wn * 64 + nt * 16 + l15;
                const float v  = acc[mt][nt][rr] + bias[nt];
                const float sp = softplus_fast(v);
                yrow[cl] = bf_lo(xrow[cl]) * sp * sv;
            }
        }
    }
}

} // namespace

extern "C" void kernel_launch(void* const* d_in, const int* in_sizes, int n_in,
                              void* d_out, int out_size, void* d_ws, size_t ws_size,
                              hipStream_t stream)
{
    const float* X  = (const float*)d_in[0];
    const float* W1 = (const float*)d_in[1];
    const float* b1 = (const float*)d_in[2];
    const float* W2 = (const float*)d_in[3];
    const float* b2 = (const float*)d_in[4];
    const float* W3 = (const float*)d_in[5];
    const float* b3 = (const float*)d_in[6];
    // d_in[7] = A is dead code in the reference.
    float* Y = (float*)d_out;

    // workspace: Xb 16MB | W1t 2MB | Sv 32KB | W2t 32KB | W3t 32KB
    char* ws = (char*)d_ws;
    __bf16* Xb  = (__bf16*)ws;
    __bf16* W1t = (__bf16*)(ws + 16777216);
    float*  Sv  = (float*) (ws + 16777216 + 2097152);
    __bf16* W2t = (__bf16*)(ws + 16777216 + 2097152 + 32768);
    __bf16* W3t = (__bf16*)(ws + 16777216 + 2097152 + 65536);

    hipLaunchKernelGGL(w23_kernel, dim3(1), dim3(256), 0, stream, W2, W3, W2t, W3t);
    hipLaunchKernelGGL(prep_kernel, dim3(768), dim3(256), 0, stream,
                       X, W1, W2t, b2, W3t, b3, Xb, W1t, Sv);
    hipLaunchKernelGGL(gemm_kernel, dim3((ROWS / 128) * (Dd / 128)), dim3(256), 0, stream,
                       Xb, W1t, Sv, b1, Y);
}

// Round 5
// 135.445 us; speedup vs baseline: 1.2395x; 1.0896x over previous
//
#include <hip/hip_runtime.h>
#include <hip/hip_bf16.h>
#include <math.h>

// y[b,l,d] = x[b,l,d] * softplus((x@W1+b1)[b,l,d]) * sum_n((x@W2+b2)*(x@W3+b3))[b,l,n]

namespace {

constexpr int Dd   = 1024;
constexpr int ROWS = 8192;

typedef __bf16 bf16x8 __attribute__((ext_vector_type(8)));
typedef float  floatx4 __attribute__((ext_vector_type(4)));

// LDS-only barrier: waits lgkmcnt(0) then s_barrier, leaves vmcnt untouched
// so prefetch global loads stay in flight across the barrier (AITER pattern).
#define LDS_BAR() asm volatile("s_waitcnt lgkmcnt(0)\n\ts_barrier" ::: "memory")

__device__ __forceinline__ float softplus_fast(float v) {
    float l = __logf(1.0f + __expf(v));
    return v > 15.0f ? v : l;
}
__device__ __forceinline__ float bf_lo(unsigned short u) {
    union { unsigned q; float f; } c; c.q = ((unsigned)u) << 16; return c.f;
}

// ---------------------------------------------------------------------------
// w23: grid 16 — W2,W3 [k][16] fp32 -> W2t,W3t [16][k] bf16. Block b covers
// k in [b*64, b*64+64). Thread (n = t>>4, 4 k's at (t&15)*4).
// ---------------------------------------------------------------------------
__global__ __launch_bounds__(256) void w23_kernel(
    const float* __restrict__ W2, const float* __restrict__ W3,
    __bf16* __restrict__ W2t, __bf16* __restrict__ W3t)
{
    const int t  = threadIdx.x;
    const int n  = t >> 4;
    const int k0 = blockIdx.x * 64 + (t & 15) * 4;
    ushort4 a, b;
    union { __bf16 h; unsigned short u; } c;
    c.h = (__bf16)W2[(size_t)(k0 + 0) * 16 + n]; a.x = c.u;
    c.h = (__bf16)W2[(size_t)(k0 + 1) * 16 + n]; a.y = c.u;
    c.h = (__bf16)W2[(size_t)(k0 + 2) * 16 + n]; a.z = c.u;
    c.h = (__bf16)W2[(size_t)(k0 + 3) * 16 + n]; a.w = c.u;
    c.h = (__bf16)W3[(size_t)(k0 + 0) * 16 + n]; b.x = c.u;
    c.h = (__bf16)W3[(size_t)(k0 + 1) * 16 + n]; b.y = c.u;
    c.h = (__bf16)W3[(size_t)(k0 + 2) * 16 + n]; b.z = c.u;
    c.h = (__bf16)W3[(size_t)(k0 + 3) * 16 + n]; b.w = c.u;
    *(ushort4*)&W2t[(size_t)n * Dd + k0] = a;
    *(ushort4*)&W3t[(size_t)n * Dd + k0] = b;
}

// ---------------------------------------------------------------------------
// prep: blocks 0..511 — 16 rows each: x fp32 -> bf16 Xb (A-frag layout) and
//       s[row] via MFMA vs W2t/W3t b128 frags. 4 waves K-split 256.
//       blocks 512..767 — W1 [k][n] fp32 -> W1t [n][k] bf16 (64x64 tiles).
// ---------------------------------------------------------------------------
__global__ __launch_bounds__(256, 4) void prep_kernel(
    const float* __restrict__ X, const float* __restrict__ W1,
    const __bf16* __restrict__ W2t, const float* __restrict__ b2,
    const __bf16* __restrict__ W3t, const float* __restrict__ b3,
    __bf16* __restrict__ Xb, __bf16* __restrict__ W1t, float* __restrict__ Sv)
{
    const int t = threadIdx.x;

    if (blockIdx.x >= 512) {
        __shared__ __bf16 tile[64][66];
        const int bidx = blockIdx.x - 512;
        const int bi = bidx >> 4, bj = bidx & 15;
        const int c = t & 63, r4 = t >> 6;
        #pragma unroll
        for (int i = 0; i < 16; ++i) {
            const int r = i * 4 + r4;
            tile[r][c] = (__bf16)W1[(size_t)(bi * 64 + r) * Dd + bj * 64 + c];
        }
        __syncthreads();
        #pragma unroll
        for (int i = 0; i < 16; ++i) {
            const int r = i * 4 + r4;
            W1t[(size_t)(bj * 64 + r) * Dd + bi * 64 + c] = tile[c][r];
        }
        return;
    }

    __shared__ float red[4][2][16][16];   // [wave][B/C][row][n]
    const int w = t >> 6, lane = t & 63;
    const int l15 = lane & 15, quad = lane >> 4;
    const int row0 = blockIdx.x * 16;
    const int kw = w * 256;
    const size_t xoff = (size_t)(row0 + l15) * Dd;
    const size_t woff = (size_t)l15 * Dd;

    floatx4 acc0 = {0.f, 0.f, 0.f, 0.f}, acc1 = {0.f, 0.f, 0.f, 0.f};
    #pragma unroll
    for (int ks = 0; ks < 8; ++ks) {
        const int k0 = kw + ks * 32 + quad * 8;
        const float4 xa = *(const float4*)&X[xoff + k0];
        const float4 xb = *(const float4*)&X[xoff + k0 + 4];
        bf16x8 af;
        af[0] = (__bf16)xa.x; af[1] = (__bf16)xa.y;
        af[2] = (__bf16)xa.z; af[3] = (__bf16)xa.w;
        af[4] = (__bf16)xb.x; af[5] = (__bf16)xb.y;
        af[6] = (__bf16)xb.z; af[7] = (__bf16)xb.w;
        *(bf16x8*)&Xb[xoff + k0] = af;
        const bf16x8 w2f = *(const bf16x8*)&W2t[woff + k0];
        const bf16x8 w3f = *(const bf16x8*)&W3t[woff + k0];
        acc0 = __builtin_amdgcn_mfma_f32_16x16x32_bf16(af, w2f, acc0, 0, 0, 0);
        acc1 = __builtin_amdgcn_mfma_f32_16x16x32_bf16(af, w3f, acc1, 0, 0, 0);
    }
    #pragma unroll
    for (int r = 0; r < 4; ++r) {
        red[w][0][quad * 4 + r][l15] = acc0[r];
        red[w][1][quad * 4 + r][l15] = acc1[r];
    }
    __syncthreads();
    {
        // thread t: row r = t>>4 (16 consecutive threads share a row), n = t&15
        const int r = t >> 4, n = t & 15;
        float B = b2[n], C = b3[n];
        #pragma unroll
        for (int ww = 0; ww < 4; ++ww) {
            B += red[ww][0][r][n];
            C += red[ww][1][r][n];
        }
        float p = B * C;
        p += __shfl_xor(p, 1); p += __shfl_xor(p, 2);
        p += __shfl_xor(p, 4); p += __shfl_xor(p, 8);
        if (n == 0) Sv[row0 + r] = p;
    }
}

// ---------------------------------------------------------------------------
// gemm: 128x128 tile, BK=32, VGPR-prefetch software pipeline. Global->VGPR
// loads for tile k+1 issued before computing tile k; ds_write + LDS-only
// barriers keep vmcnt in flight across the barrier. XOR-slot swizzled LDS
// (R2-verified mapping, conflict-free). Fused epilogue.
// ---------------------------------------------------------------------------
__global__ __launch_bounds__(256, 2) void gemm_kernel(
    const __bf16* __restrict__ Xb, const __bf16* __restrict__ W1t,
    const float* __restrict__ Sv, const float* __restrict__ b1,
    float* __restrict__ Y)
{
    __shared__ __attribute__((aligned(16))) __bf16 lds[8192]; // A:[0,4096) B:[4096,8192)
    const int t = threadIdx.x, lane = t & 63;
    const int w = t >> 6, wm = w & 1, wn = w >> 1;
    const int l15 = lane & 15, quad = lane >> 4;
    const int cb = blockIdx.x & 7, rb = blockIdx.x >> 3;  // cb ~ XCD: B-slice L2-resident
    const int row0 = rb * 128, col0 = cb * 128;

    floatx4 acc[4][4] = {};

    // R2-verified staging map: slot u -> (rowL, chunk) with c4 = (u&7)^((u>>3)&7)
    const __bf16* gA[2]; const __bf16* gB[2];
    int dA[2], dB[2];
    #pragma unroll
    for (int r = 0; r < 2; ++r) {
        const int u = r * 256 + t;
        const int p = u >> 3, s = u & 7, c4 = s ^ (p & 7);
        const int rowL = 2 * p + (c4 >> 2), chk = c4 & 3;
        gA[r] = Xb  + (size_t)(row0 + rowL) * Dd + chk * 8;
        gB[r] = W1t + (size_t)(col0 + rowL) * Dd + chk * 8;
        dA[r] = u * 8;
        dB[r] = 4096 + u * 8;
    }

    bf16x8 bufA[2][2], bufB[2][2];

    auto gload = [&](int buf, int k) {
        #pragma unroll
        for (int r = 0; r < 2; ++r) {
            bufA[buf][r] = *(const bf16x8*)(gA[r] + k);
            bufB[buf][r] = *(const bf16x8*)(gB[r] + k);
        }
    };
    auto store_lds = [&](int buf) {
        #pragma unroll
        for (int r = 0; r < 2; ++r) {
            *(bf16x8*)&lds[dA[r]] = bufA[buf][r];
            *(bf16x8*)&lds[dB[r]] = bufB[buf][r];
        }
    };
    auto compute = [&]() {
        bf16x8 af[4], bfr[4];
        #pragma unroll
        for (int mt = 0; mt < 4; ++mt) {
            const int rl = wm * 64 + mt * 16 + l15;
            const int p = rl >> 1, c4 = ((rl & 1) << 2) | quad, s = c4 ^ (p & 7);
            af[mt] = *(const bf16x8*)&lds[p * 64 + s * 8];
        }
        #pragma unroll
        for (int nt = 0; nt < 4; ++nt) {
            const int nl = wn * 64 + nt * 16 + l15;
            const int p = nl >> 1, c4 = ((nl & 1) << 2) | quad, s = c4 ^ (p & 7);
            bfr[nt] = *(const bf16x8*)&lds[4096 + p * 64 + s * 8];
        }
        #pragma unroll
        for (int mt = 0; mt < 4; ++mt)
            #pragma unroll
            for (int nt = 0; nt < 4; ++nt)
                acc[mt][nt] = __builtin_amdgcn_mfma_f32_16x16x32_bf16(
                    af[mt], bfr[nt], acc[mt][nt], 0, 0, 0);
    };

    gload(0, 0);
    for (int k0 = 0; k0 < Dd; k0 += 64) {
        gload(1, k0 + 32);          // always valid (<= Dd-32)
        LDS_BAR();                  // prev compute done reading LDS
        store_lds(0);               // compiler: vmcnt(4) — buf1 stays in flight
        LDS_BAR();                  // LDS visible to all waves
        compute();
        if (k0 + 64 < Dd) gload(0, k0 + 64);
        LDS_BAR();
        store_lds(1);
        LDS_BAR();
        compute();
    }

    // epilogue: C/D layout col = l15, row = quad*4 + rr
    float bias[4];
    #pragma unroll
    for (int nt = 0; nt < 4; ++nt) bias[nt] = b1[col0 + wn * 64 + nt * 16 + l15];

    #pragma unroll
    for (int mt = 0; mt < 4; ++mt) {
        #pragma unroll
        for (int rr = 0; rr < 4; ++rr) {
            const int row = row0 + wm * 64 + mt * 16 + quad * 4 + rr;
            const float sv = Sv[row];
            const unsigned short* xrow =
                (const unsigned short*)(Xb + (size_t)row * Dd + col0);
            float* yrow = Y + (size_t)row * Dd + col0;
            #pragma unroll
            for (int nt = 0; nt < 4; ++nt) {
                const int cl = wn * 64 + nt * 16 + l15;
                const float v  = acc[mt][nt][rr] + bias[nt];
                const float sp = softplus_fast(v);
                yrow[cl] = bf_lo(xrow[cl]) * sp * sv;
            }
        }
    }
}

} // namespace

extern "C" void kernel_launch(void* const* d_in, const int* in_sizes, int n_in,
                              void* d_out, int out_size, void* d_ws, size_t ws_size,
                              hipStream_t stream)
{
    const float* X  = (const float*)d_in[0];
    const float* W1 = (const float*)d_in[1];
    const float* b1 = (const float*)d_in[2];
    const float* W2 = (const float*)d_in[3];
    const float* b2 = (const float*)d_in[4];
    const float* W3 = (const float*)d_in[5];
    const float* b3 = (const float*)d_in[6];
    // d_in[7] = A is dead code in the reference.
    float* Y = (float*)d_out;

    // workspace: Xb 16MB | W1t 2MB | Sv 32KB | W2t 32KB | W3t 32KB
    char* ws = (char*)d_ws;
    __bf16* Xb  = (__bf16*)ws;
    __bf16* W1t = (__bf16*)(ws + 16777216);
    float*  Sv  = (float*) (ws + 16777216 + 2097152);
    __bf16* W2t = (__bf16*)(ws + 16777216 + 2097152 + 32768);
    __bf16* W3t = (__bf16*)(ws + 16777216 + 2097152 + 65536);

    hipLaunchKernelGGL(w23_kernel, dim3(16), dim3(256), 0, stream, W2, W3, W2t, W3t);
    hipLaunchKernelGGL(prep_kernel, dim3(768), dim3(256), 0, stream,
                       X, W1, W2t, b2, W3t, b3, Xb, W1t, Sv);
    hipLaunchKernelGGL(gemm_kernel, dim3((ROWS / 128) * (Dd / 128)), dim3(256), 0, stream,
                       Xb, W1t, Sv, b1, Y);
}